// Round 1
// 1001.671 us; speedup vs baseline: 1.1486x; 1.1486x over previous
//
#include <hip/hip_runtime.h>
#include <math.h>
#include <cstdint>

#define L 2048
#define E 768
#define NH 12
#define NL 4
#define FFN 2048
#define VOC 4096
#define LDQKV (3*E)
#define LOG2E 1.4426950408889634f

typedef unsigned short u16;
typedef __bf16 bf16x8 __attribute__((ext_vector_type(8)));
typedef float f32x4 __attribute__((ext_vector_type(4)));

__device__ __forceinline__ float bf2f(u16 u){
  union { unsigned int i; float f; } v; v.i = ((unsigned int)u) << 16; return v.f;
}
__device__ __forceinline__ u16 f2bf(float f){
  union { float fl; unsigned int i; } v; v.fl = f;
  unsigned int r = v.i + 0x7fffu + ((v.i >> 16) & 1u);
  return (u16)(r >> 16);
}
__device__ __forceinline__ float gelu_exact(float x){
  return 0.5f * x * (1.0f + erff(x * 0.70710678118654752f));
}
__device__ __forceinline__ float ldw(const void* p, size_t i, int f32w){
  return f32w ? ((const float*)p)[i] : bf2f(((const u16*)p)[i]);
}

#define MFMA_BF16(a,b,c) __builtin_amdgcn_mfma_f32_16x16x32_bf16(a,b,c,0,0,0)

// async global->LDS, 16B/lane; LDS dest = wave-uniform base + lane*16 (m97/m104)
__device__ __forceinline__ void gload16(const u16* g, const u16* l){
  __builtin_amdgcn_global_load_lds(
      (__attribute__((address_space(1))) void*)(uintptr_t)(const void*)g,
      (__attribute__((address_space(3))) void*)(unsigned int)(uintptr_t)(const void*)l,
      16, 0, 0);
}

// ---------------- dtype detect ----------------
__global__ __launch_bounds__(256) void detect_kernel(const u16* __restrict__ emb,
                                                     unsigned int* __restrict__ flag){
  __shared__ int s;
  if (threadIdx.x == 0) s = 0;
  __syncthreads();
  float mx = 0.f;
  for (int i = threadIdx.x; i < 16384; i += 256)
    mx = fmaxf(mx, fabsf(bf2f(emb[2*i])));
  if (mx > 1e4f) s = 1;
  __syncthreads();
  if (threadIdx.x == 0) *flag = (unsigned int)s;
}

// ---------------- weight cast -> canonical bf16 ----------------
__global__ __launch_bounds__(256) void cast4_kernel(const void* __restrict__ src,
                                                    u16* __restrict__ dst, int n4,
                                                    const unsigned int* __restrict__ flag){
  int i4 = blockIdx.x * 256 + threadIdx.x;
  if (i4 >= n4) return;
  size_t i = (size_t)i4 * 4;
  ushort4 o;
  if (*flag){
    const float4 f = ((const float4*)src)[i4];
    o.x = f2bf(f.x); o.y = f2bf(f.y); o.z = f2bf(f.z); o.w = f2bf(f.w);
  } else {
    o = ((const ushort4*)src)[i4];
  }
  *(ushort4*)(dst + i) = o;
}

// ---------------- per-head ALiBi+pad bias in exp2 domain ----------------
// biasH[h][k] = (slope_h * k + (amask[k]==0 ? 1 : 0)) * log2(e)
// (row-constant -slope*q term dropped: softmax-invariant)
__global__ __launch_bounds__(256) void bias_kernel(const int* __restrict__ amask,
                                                   float* __restrict__ biasH){
  int i = blockIdx.x * 256 + threadIdx.x;     // NH*L
  int h = i >> 11;
  int k = i & (L - 1);
  float slope = exp2f(h < 8 ? -(float)(h+1) : -0.5f - (float)(h-8));
  float pad = (amask[k] == 0) ? 1.0f : 0.0f;
  biasH[i] = (slope * (float)k + pad) * LOG2E;
}

// ---------------- embedding gather -> f32 residual ----------------
__global__ __launch_bounds__(256) void embed_kernel(const int* __restrict__ tok,
                                                    const void* __restrict__ emb,
                                                    const unsigned int* __restrict__ flag,
                                                    float* __restrict__ x){
  const int f32w = (int)*flag;
  int idx = blockIdx.x * 256 + threadIdx.x;
  int l = idx / E, e = idx - l * E;
  x[idx] = ldw(emb, (size_t)tok[l] * E + e, f32w);
}

// ---------------- LayerNorm: f32 in, bf16 out ----------------
__global__ __launch_bounds__(256) void ln_kernel(const float* __restrict__ x,
                                                 const void* __restrict__ g,
                                                 const void* __restrict__ b,
                                                 size_t goff, size_t boff,
                                                 const unsigned int* __restrict__ flag,
                                                 u16* __restrict__ o){
  const int f32w = (int)*flag;
  const int wave = threadIdx.x >> 6, lane = threadIdx.x & 63;
  const int row = blockIdx.x * 4 + wave;
  const float* xr = x + (size_t)row * E;
  float v[12]; float s = 0.f;
  #pragma unroll
  for (int i = 0; i < 12; i++){ v[i] = xr[lane + i*64]; s += v[i]; }
  #pragma unroll
  for (int off = 32; off > 0; off >>= 1) s += __shfl_xor(s, off);
  const float mean = s * (1.0f / E);
  float vs = 0.f;
  #pragma unroll
  for (int i = 0; i < 12; i++){ float d = v[i] - mean; vs += d * d; }
  #pragma unroll
  for (int off = 32; off > 0; off >>= 1) vs += __shfl_xor(vs, off);
  const float rstd = rsqrtf(vs * (1.0f / E) + 1e-5f);
  u16* orow = o + (size_t)row * E;
  #pragma unroll
  for (int i = 0; i < 12; i++){
    int c = lane + i*64;
    orow[c] = f2bf((v[i] - mean) * rstd * ldw(g, goff + c, f32w) + ldw(b, boff + c, f32w));
  }
}

// ---------------- MFMA GEMM, software-pipelined (AITER-style) ----------------
template<int EPI>
__global__ __launch_bounds__(256)
void gemm_bt(const u16* __restrict__ A, const u16* __restrict__ Bm,
             const void* __restrict__ bias, size_t biasoff,
             const unsigned int* __restrict__ flag,
             u16* __restrict__ outb, float* __restrict__ outf,
             int M, int N, int K){
  __shared__ __align__(16) u16 As[2*128*32];
  __shared__ __align__(16) u16 Bs[2*128*32];
  const int t = threadIdx.x;
  const int lane = t & 63;
  const int col = lane & 15, quad = lane >> 4;
  const int wave = t >> 6;
  const int wr = (wave >> 1) * 64, wc = (wave & 1) * 64;
  const int row0 = blockIdx.y * 128, col0 = blockIdx.x * 128;
  const int f32w = (int)*flag;

  int kb = 0, ke = K;
  if (gridDim.z > 1){ const int kc = K / (int)gridDim.z; kb = blockIdx.z * kc; ke = kb + kc; }

  const int sr = t >> 2;
  const int sc = (t & 3) * 8;
  const u16* Ag = A + (size_t)(row0 + sr) * K + sc;
  const u16* Bg = Bm + (size_t)(col0 + sr) * K + sc;

  f32x4 acc[4][4];
  #pragma unroll
  for (int i = 0; i < 4; i++)
    #pragma unroll
    for (int j = 0; j < 4; j++) acc[i][j] = (f32x4){0.f,0.f,0.f,0.f};

  gload16(Ag + kb,                As + wave*512);
  gload16(Ag + (size_t)64*K + kb, As + wave*512 + 2048);
  gload16(Bg + kb,                Bs + wave*512);
  gload16(Bg + (size_t)64*K + kb, Bs + wave*512 + 2048);

  int p = 0;
  for (int k0 = kb; k0 < ke; k0 += 32, p ^= 1){
    if (k0 + 32 < ke){
      const int nx = (p ^ 1) * 4096;
      gload16(Ag + k0 + 32,                As + nx + wave*512);
      gload16(Ag + (size_t)64*K + k0 + 32, As + nx + wave*512 + 2048);
      gload16(Bg + k0 + 32,                Bs + nx + wave*512);
      gload16(Bg + (size_t)64*K + k0 + 32, Bs + nx + wave*512 + 2048);
      asm volatile("s_waitcnt vmcnt(4)\n\ts_barrier" ::: "memory");
    } else {
      asm volatile("s_waitcnt vmcnt(0)\n\ts_barrier" ::: "memory");
    }
    const u16* Ab = As + p*4096;
    const u16* Bb = Bs + p*4096;
    bf16x8 af[4], bfr[4];
    #pragma unroll
    for (int i = 0; i < 4; i++)
      af[i] = *(const bf16x8*)(Ab + (wr + i*16 + col)*32 + quad*8);
    #pragma unroll
    for (int j = 0; j < 4; j++)
      bfr[j] = *(const bf16x8*)(Bb + (wc + j*16 + col)*32 + quad*8);
    #pragma unroll
    for (int i = 0; i < 4; i++)
      #pragma unroll
      for (int j = 0; j < 4; j++)
        acc[i][j] = MFMA_BF16(af[i], bfr[j], acc[i][j]);
    asm volatile("s_waitcnt lgkmcnt(0)\n\ts_barrier" ::: "memory");
  }

  #pragma unroll
  for (int j = 0; j < 4; j++){
    const int c = col0 + wc + j*16 + col;
    const float bb = (gridDim.z > 1 && blockIdx.z != 0) ? 0.f : ldw(bias, biasoff + c, f32w);
    #pragma unroll
    for (int i = 0; i < 4; i++){
      const int r0 = row0 + wr + i*16 + quad*4;
      #pragma unroll
      for (int rr = 0; rr < 4; rr++){
        const float v = acc[i][j][rr] + bb;
        const size_t idx = (size_t)(r0 + rr) * N + c;
        if (EPI == 0)      outb[idx] = f2bf(v);
        else if (EPI == 1) atomicAdd(&outf[idx], v);
        else if (EPI == 2) outf[idx] = gelu_exact(v);
        else if (EPI == 3) outb[idx] = f2bf(bf2f(outb[idx]) * gelu_exact(v));
        else { if (f32w) outf[idx] = v; else outb[idx] = f2bf(v); }
      }
    }
  }
}

// ---------------- V transpose: Vt[h][d][j] ----------------
__global__ __launch_bounds__(256)
void vt_kernel(const u16* __restrict__ qkv, u16* __restrict__ Vt){
  const int h = blockIdx.x;
  const int t = threadIdx.x;
  const int d = t & 63;
  const int j0 = blockIdx.y * 32 + (t >> 6) * 8;
  u16 tmp[8];
  #pragma unroll
  for (int jj = 0; jj < 8; jj++)
    tmp[jj] = qkv[(size_t)(j0 + jj) * LDQKV + 2*E + h*64 + d];
  *(ushort4*)(Vt + (size_t)(h*64 + d) * L + j0)     = *(ushort4*)(tmp);
  *(ushort4*)(Vt + (size_t)(h*64 + d) * L + j0 + 4) = *(ushort4*)(tmp + 4);
}

// ---------------- MFMA flash attention, v2 ----------------
// 8 waves: waves 0-3 process keys [0,1024), waves 4-7 keys [1024,2048) for the
// same 64 q rows (KV-split x2 -> 2x occupancy). Swapped QK^T (mfma(K,Q)) makes
// each lane own one q row (q = q0+col): softmax max/sum = in-lane tree + 2
// shfl_xor; P written as packed b64 (v_cvt_pk_bf16_f32) in A-fragment order.
// exp2-domain scores: sv = s*scale*log2e + biasH[h][k]; online partials merged
// across the two groups in LDS at the end.
__global__ __launch_bounds__(512, 4)
void attn_mfma(const u16* __restrict__ qkv, const u16* __restrict__ Vt,
               const float* __restrict__ biasH, u16* __restrict__ outp){
  const int head = blockIdx.x;
  const int t = threadIdx.x;
  const int wave = t >> 6, lane = t & 63;
  const int grp = wave >> 2, w4 = wave & 3;
  const int col = lane & 15, quad = lane >> 4;
  const int q0 = blockIdx.y * 64 + w4 * 16;
  const int kbeg = grp * (L/2);

  __shared__ __align__(16) u16 Kf[2][64*64];   // per group: [key chunk][col][8]
  __shared__ __align__(16) u16 Vf[2][64*64];
  __shared__ __align__(16) u16 Pf[8][16*64];   // per wave, A-fragment order
  u16* Kg_ = Kf[grp];
  u16* Vg_ = Vf[grp];
  u16* P = Pf[wave];

  const float scale2 = 0.125f * LOG2E;
  const float* bH = biasH + (size_t)head * L + kbeg;

  const u16* qrow = qkv + (size_t)(q0 + col) * LDQKV + head*64;
  const bf16x8 qf0 = *(const bf16x8*)(qrow + quad*8);
  const bf16x8 qf1 = *(const bf16x8*)(qrow + 32 + quad*8);

  const u16* kbase  = qkv + E + head*64;
  const u16* vtbase = Vt + (size_t)(head*64) * L;

  const int tg = t & 255;              // staging id within group
  const int skey = tg >> 2;            // K: key row / V: d row
  const int stc  = (tg & 3) * 16;      // 32B chunk-pair offset
  const int kw0  = (((skey >> 4)*8 + (tg & 3)*2)*16 + (skey & 15))*8;
  const int kw1  = kw0 + 128;

  float m_i = -1e30f, l_i = 0.f;
  f32x4 oacc[4];
  #pragma unroll
  for (int nt = 0; nt < 4; nt++) oacc[nt] = (f32x4){0.f,0.f,0.f,0.f};

  // preload tile 0 of this group's half into regs
  const u16* kg = kbase + (size_t)(kbeg + skey) * LDQKV + stc;
  const u16* vg = vtbase + (size_t)skey * L + kbeg + stc;
  bf16x8 kr0 = *(const bf16x8*)(kg), kr1 = *(const bf16x8*)(kg + 8);
  bf16x8 vr0 = *(const bf16x8*)(vg), vr1 = *(const bf16x8*)(vg + 8);

  for (int kt = 0; kt < L/2; kt += 64){
    *(bf16x8*)(Kg_ + kw0) = kr0;
    *(bf16x8*)(Kg_ + kw1) = kr1;
    *(bf16x8*)(Vg_ + kw0) = vr0;
    *(bf16x8*)(Vg_ + kw1) = vr1;
    asm volatile("s_waitcnt lgkmcnt(0)\n\ts_barrier" ::: "memory");
    if (kt + 64 < L/2){
      const u16* kg2 = kbase + (size_t)(kbeg + kt + 64 + skey) * LDQKV + stc;
      const u16* vg2 = vtbase + (size_t)skey * L + kbeg + kt + 64 + stc;
      kr0 = *(const bf16x8*)(kg2); kr1 = *(const bf16x8*)(kg2 + 8);
      vr0 = *(const bf16x8*)(vg2); vr1 = *(const bf16x8*)(vg2 + 8);
    }

    // ---- swapped QK^T: s[nt][r] = S[k=kt+nt*16+quad*4+r][q=q0+col] ----
    f32x4 s[4];
    #pragma unroll
    for (int nt = 0; nt < 4; nt++){
      const bf16x8 kf0 = *(const bf16x8*)(Kg_ + nt*1024 + lane*8);
      const bf16x8 kf1 = *(const bf16x8*)(Kg_ + nt*1024 + 512 + lane*8);
      f32x4 z = (f32x4){0.f,0.f,0.f,0.f};
      z = MFMA_BF16(kf0, qf0, z);
      z = MFMA_BF16(kf1, qf1, z);
      s[nt] = z;
    }
    // ---- bias: 1 fma per score ----
    float sv[16];
    #pragma unroll
    for (int nt = 0; nt < 4; nt++){
      const float4 bv = *(const float4*)(bH + kt + nt*16 + quad*4);
      sv[nt*4+0] = fmaf(s[nt][0], scale2, bv.x);
      sv[nt*4+1] = fmaf(s[nt][1], scale2, bv.y);
      sv[nt*4+2] = fmaf(s[nt][2], scale2, bv.z);
      sv[nt*4+3] = fmaf(s[nt][3], scale2, bv.w);
    }
    // ---- in-lane max tree + cross-quad reduce (q fixed per lane) ----
    float t8[8];
    #pragma unroll
    for (int i = 0; i < 8; i++) t8[i] = fmaxf(sv[i], sv[i+8]);
    float t4a = fmaxf(t8[0], t8[4]), t4b = fmaxf(t8[1], t8[5]);
    float t4c = fmaxf(t8[2], t8[6]), t4d = fmaxf(t8[3], t8[7]);
    float mx = fmaxf(fmaxf(t4a, t4b), fmaxf(t4c, t4d));
    mx = fmaxf(mx, __shfl_xor(mx, 16));
    mx = fmaxf(mx, __shfl_xor(mx, 32));
    const float mnew = fmaxf(m_i, mx);
    const float a = exp2f(m_i - mnew);
    m_i = mnew;
    // ---- exp2 + packed P write (4x ds_write_b64/tile) ----
    float ps = 0.f;
    #pragma unroll
    for (int nt = 0; nt < 4; nt++){
      const float e0 = exp2f(sv[nt*4+0] - mnew);
      const float e1 = exp2f(sv[nt*4+1] - mnew);
      const float e2 = exp2f(sv[nt*4+2] - mnew);
      const float e3 = exp2f(sv[nt*4+3] - mnew);
      unsigned int plo, phi;
      asm("v_cvt_pk_bf16_f32 %0, %1, %2" : "=v"(plo) : "v"(e0), "v"(e1));
      asm("v_cvt_pk_bf16_f32 %0, %1, %2" : "=v"(phi) : "v"(e2), "v"(e3));
      *(uint2*)(P + ((nt*2 + (quad >> 1))*16 + col)*8 + (quad & 1)*4) =
          make_uint2(plo, phi);
      ps += (e0 + e1) + (e2 + e3);
    }
    ps += __shfl_xor(ps, 16);
    ps += __shfl_xor(ps, 32);
    l_i = l_i * a + ps;
    // rescale O rows (q = q0+quad*4+r -> fetch a from lane quad*4+r)
    float al[4];
    #pragma unroll
    for (int r = 0; r < 4; r++) al[r] = __shfl(a, quad*4 + r);
    #pragma unroll
    for (int nt = 0; nt < 4; nt++)
      #pragma unroll
      for (int r = 0; r < 4; r++) oacc[nt][r] *= al[r];

    // ---- PV: O += P[16x64] @ V[64x64] ----
    asm volatile("s_waitcnt lgkmcnt(0)" ::: "memory");
    const bf16x8 pa0 = *(const bf16x8*)(P + lane*8);
    const bf16x8 pa1 = *(const bf16x8*)(P + 512 + lane*8);
    #pragma unroll
    for (int nt = 0; nt < 4; nt++){
      const bf16x8 vb0 = *(const bf16x8*)(Vg_ + nt*1024 + lane*8);
      const bf16x8 vb1 = *(const bf16x8*)(Vg_ + nt*1024 + 512 + lane*8);
      oacc[nt] = MFMA_BF16(pa0, vb0, oacc[nt]);
      oacc[nt] = MFMA_BF16(pa1, vb1, oacc[nt]);
    }
    asm volatile("s_waitcnt lgkmcnt(0)\n\ts_barrier" ::: "memory");
  }

  // ---- merge the two KV halves (after final barrier K/V LDS is dead) ----
  float* cO = (float*)&Kf[0][0];   // 4 pairs x 64 lanes x 16 f32 = 16 KB
  float* cm = (float*)&Vf[0][0];   // 4 x 16
  float* cl = cm + 64;
  if (grp == 1){
    #pragma unroll
    for (int nt = 0; nt < 4; nt++)
      #pragma unroll
      for (int r = 0; r < 4; r++)
        cO[(size_t)(w4*64 + lane)*16 + nt*4 + r] = oacc[nt][r];
    if (quad == 0){ cm[w4*16 + col] = m_i; cl[w4*16 + col] = l_i; }
  }
  __syncthreads();
  if (grp == 0){
    const float m1 = cm[w4*16 + col], l1 = cl[w4*16 + col];
    const float M = fmaxf(m_i, m1);
    const float c0 = exp2f(m_i - M), c1 = exp2f(m1 - M);
    const float inv = 1.0f / (l_i * c0 + l1 * c1);
    const float w0 = c0 * inv, w1 = c1 * inv;
    float s0[4], s1[4];
    #pragma unroll
    for (int r = 0; r < 4; r++){
      s0[r] = __shfl(w0, quad*4 + r);
      s1[r] = __shfl(w1, quad*4 + r);
    }
    #pragma unroll
    for (int nt = 0; nt < 4; nt++)
      #pragma unroll
      for (int r = 0; r < 4; r++){
        const float o1 = cO[(size_t)(w4*64 + lane)*16 + nt*4 + r];
        const int row = q0 + quad*4 + r;
        outp[(size_t)row * E + head*64 + nt*16 + col] =
            f2bf(oacc[nt][r] * s0[r] + o1 * s1[r]);
      }
  }
}

extern "C" void kernel_launch(void* const* d_in, const int* in_sizes, int n_in,
                              void* d_out, int out_size, void* d_ws, size_t ws_size,
                              hipStream_t stream){
  const int* tokens = (const int*)d_in[0];
  const int* amask  = (const int*)d_in[1];

  // ---- ws: flag | biasH | x f32 | hbuf bf16 | Vt bf16 | weight casts (~76.8 MB) ----
  unsigned int* flag = (unsigned int*)d_ws;
  float* biasH = (float*)((char*)d_ws + 256);
  float* x   = biasH + (size_t)NH*L;
  u16* hbuf  = (u16*)(x + (size_t)L*E);
  u16* vtb   = hbuf + (size_t)L*E;
  u16* wc    = vtb + (size_t)NH*64*L;

  const size_t N_INW  = (size_t)NL*3*E*E;
  const size_t N_OUTW = (size_t)NL*E*E;
  const size_t N_FW1  = (size_t)NL*2*FFN*E;
  const size_t N_FW2  = (size_t)NL*E*FFN;
  const size_t N_MW1  = (size_t)E*E;
  const size_t N_MW2  = (size_t)VOC*E;
  u16* in_w  = wc;                 wc += N_INW;
  u16* out_w = wc;                 wc += N_OUTW;
  u16* ffw1  = wc;                 wc += N_FW1;
  u16* ffw2  = wc;                 wc += N_FW2;
  u16* mw1   = wc;                 wc += N_MW1;
  u16* mw2   = wc;                 wc += N_MW2;

  // ---- activations in d_out (high-water 16.8 MB) ----
  u16* qkvb  = (u16*)d_out;
  u16* attnb = (u16*)d_out + (size_t)L*LDQKV;
  u16* abuf  = (u16*)d_out;
  float* tbuf = (float*)d_out;

  detect_kernel<<<1, 256, 0, stream>>>((const u16*)d_in[2], flag);
  bias_kernel<<<NH*L/256, 256, 0, stream>>>(amask, biasH);
  cast4_kernel<<<(int)(N_INW/1024), 256, 0, stream>>>(d_in[5],  in_w,  (int)(N_INW/4),  flag);
  cast4_kernel<<<(int)(N_OUTW/1024),256, 0, stream>>>(d_in[7],  out_w, (int)(N_OUTW/4), flag);
  cast4_kernel<<<(int)(N_FW1/1024), 256, 0, stream>>>(d_in[11], ffw1,  (int)(N_FW1/4),  flag);
  cast4_kernel<<<(int)(N_FW2/1024), 256, 0, stream>>>(d_in[13], ffw2,  (int)(N_FW2/4),  flag);
  cast4_kernel<<<(int)(N_MW1/1024), 256, 0, stream>>>(d_in[17], mw1,   (int)(N_MW1/4),  flag);
  cast4_kernel<<<(int)(N_MW2/1024), 256, 0, stream>>>(d_in[21], mw2,   (int)(N_MW2/4),  flag);

  embed_kernel<<<L*E/256, 256, 0, stream>>>(tokens, d_in[2], flag, x);

  for (int ly = 0; ly < NL; ly++){
    ln_kernel<<<L/4, 256, 0, stream>>>(x, d_in[3], d_in[4],
        (size_t)ly*E, (size_t)ly*E, flag, hbuf);
    gemm_bt<0><<<dim3(3*E/128, L/128), 256, 0, stream>>>(hbuf, in_w + (size_t)ly*3*E*E,
        d_in[6], (size_t)ly*3*E, flag, qkvb, nullptr, L, 3*E, E);
    vt_kernel<<<dim3(NH, L/32), 256, 0, stream>>>(qkvb, vtb);
    attn_mfma<<<dim3(NH, L/64), 512, 0, stream>>>(qkvb, vtb, biasH, attnb);
    gemm_bt<1><<<dim3(E/128, L/128, 2), 256, 0, stream>>>(attnb, out_w + (size_t)ly*E*E,
        d_in[8], (size_t)ly*E, flag, nullptr, x, L, E, E);
    ln_kernel<<<L/4, 256, 0, stream>>>(x, d_in[9], d_in[10],
        (size_t)ly*E, (size_t)ly*E, flag, hbuf);
    gemm_bt<0><<<dim3(FFN/128, L/128), 256, 0, stream>>>(hbuf,
        ffw1 + (size_t)ly*2*FFN*E, d_in[12], (size_t)ly*2*FFN, flag,
        abuf, nullptr, L, FFN, E);
    gemm_bt<3><<<dim3(FFN/128, L/128), 256, 0, stream>>>(hbuf,
        ffw1 + (size_t)ly*2*FFN*E + (size_t)FFN*E, d_in[12], (size_t)ly*2*FFN + FFN, flag,
        abuf, nullptr, L, FFN, E);
    gemm_bt<1><<<dim3(E/128, L/128, 2), 256, 0, stream>>>(abuf, ffw2 + (size_t)ly*E*FFN,
        d_in[14], (size_t)ly*E, flag, nullptr, x, L, E, FFN);
  }
  ln_kernel<<<L/4, 256, 0, stream>>>(x, d_in[15], d_in[16], 0, 0, flag, hbuf);
  gemm_bt<2><<<dim3(E/128, L/128), 256, 0, stream>>>(hbuf, mw1,
      d_in[18], 0, flag, nullptr, tbuf, L, E, E);
  ln_kernel<<<L/4, 256, 0, stream>>>(tbuf, d_in[19], d_in[20], 0, 0, flag, hbuf);
  gemm_bt<4><<<dim3(VOC/128, L/128), 256, 0, stream>>>(hbuf, mw2,
      d_in[22], 0, flag, (u16*)d_out, (float*)d_out, L, VOC, E);
}

// Round 3
// 954.031 us; speedup vs baseline: 1.2060x; 1.0499x over previous
//
#include <hip/hip_runtime.h>
#include <math.h>
#include <cstdint>

#define L 2048
#define E 768
#define NH 12
#define NL 4
#define FFN 2048
#define VOC 4096
#define LDQKV (3*E)
#define LOG2E 1.4426950408889634f

typedef unsigned short u16;
typedef __bf16 bf16x8 __attribute__((ext_vector_type(8)));
typedef float f32x4 __attribute__((ext_vector_type(4)));

__device__ __forceinline__ float bf2f(u16 u){
  union { unsigned int i; float f; } v; v.i = ((unsigned int)u) << 16; return v.f;
}
__device__ __forceinline__ u16 f2bf(float f){
  union { float fl; unsigned int i; } v; v.fl = f;
  unsigned int r = v.i + 0x7fffu + ((v.i >> 16) & 1u);
  return (u16)(r >> 16);
}
__device__ __forceinline__ float gelu_exact(float x){
  return 0.5f * x * (1.0f + erff(x * 0.70710678118654752f));
}
__device__ __forceinline__ float ldw(const void* p, size_t i, int f32w){
  return f32w ? ((const float*)p)[i] : bf2f(((const u16*)p)[i]);
}

#define MFMA_BF16(a,b,c) __builtin_amdgcn_mfma_f32_16x16x32_bf16(a,b,c,0,0,0)

// async global->LDS, 16B/lane; LDS dest = wave-uniform base + lane*16 (m97/m104);
// global source address is per-lane (m173) -> pre-swizzled source + linear dest.
__device__ __forceinline__ void gload16(const u16* g, const u16* l){
  __builtin_amdgcn_global_load_lds(
      (__attribute__((address_space(1))) void*)(uintptr_t)(const void*)g,
      (__attribute__((address_space(3))) void*)(unsigned int)(uintptr_t)(const void*)l,
      16, 0, 0);
}

// ---------------- dtype detect ----------------
__global__ __launch_bounds__(256) void detect_kernel(const u16* __restrict__ emb,
                                                     unsigned int* __restrict__ flag){
  __shared__ int s;
  if (threadIdx.x == 0) s = 0;
  __syncthreads();
  float mx = 0.f;
  for (int i = threadIdx.x; i < 16384; i += 256)
    mx = fmaxf(mx, fabsf(bf2f(emb[2*i])));
  if (mx > 1e4f) s = 1;
  __syncthreads();
  if (threadIdx.x == 0) *flag = (unsigned int)s;
}

// ---------------- all weight casts -> canonical bf16, one launch ----------------
__global__ __launch_bounds__(256)
void cast_all(const void* __restrict__ s0, const void* __restrict__ s1,
              const void* __restrict__ s2, const void* __restrict__ s3,
              const void* __restrict__ s4, const void* __restrict__ s5,
              u16* __restrict__ dst,
              int o1, int o2, int o3, int o4, int o5, int o6,
              const unsigned int* __restrict__ flag){
  int i4 = blockIdx.x * 256 + threadIdx.x;
  if (i4 >= o6) return;
  const void* src; int base;
  if      (i4 < o1){ src = s0; base = 0;  }
  else if (i4 < o2){ src = s1; base = o1; }
  else if (i4 < o3){ src = s2; base = o2; }
  else if (i4 < o4){ src = s3; base = o3; }
  else if (i4 < o5){ src = s4; base = o4; }
  else             { src = s5; base = o5; }
  ushort4 o;
  if (*flag){
    const float4 f = ((const float4*)src)[i4 - base];
    o.x = f2bf(f.x); o.y = f2bf(f.y); o.z = f2bf(f.z); o.w = f2bf(f.w);
  } else {
    o = ((const ushort4*)src)[i4 - base];
  }
  *(ushort4*)(dst + (size_t)i4 * 4) = o;
}

// ---------------- per-head ALiBi+pad bias in exp2 domain ----------------
__global__ __launch_bounds__(256) void bias_kernel(const int* __restrict__ amask,
                                                   float* __restrict__ biasH){
  int i = blockIdx.x * 256 + threadIdx.x;     // NH*L
  int h = i >> 11;
  int k = i & (L - 1);
  float slope = exp2f(h < 8 ? -(float)(h+1) : -0.5f - (float)(h-8));
  float pad = (amask[k] == 0) ? 1.0f : 0.0f;
  biasH[i] = (slope * (float)k + pad) * LOG2E;
}

// ---------------- embedding gather -> f32 residual ----------------
__global__ __launch_bounds__(256) void embed_kernel(const int* __restrict__ tok,
                                                    const void* __restrict__ emb,
                                                    const unsigned int* __restrict__ flag,
                                                    float* __restrict__ x){
  const int f32w = (int)*flag;
  int idx = blockIdx.x * 256 + threadIdx.x;
  int l = idx / E, e = idx - l * E;
  x[idx] = ldw(emb, (size_t)tok[l] * E + e, f32w);
}

// ---------------- LayerNorm: f32 in, bf16 out ----------------
__global__ __launch_bounds__(256) void ln_kernel(const float* __restrict__ x,
                                                 const void* __restrict__ g,
                                                 const void* __restrict__ b,
                                                 size_t goff, size_t boff,
                                                 const unsigned int* __restrict__ flag,
                                                 u16* __restrict__ o){
  const int f32w = (int)*flag;
  const int wave = threadIdx.x >> 6, lane = threadIdx.x & 63;
  const int row = blockIdx.x * 4 + wave;
  const float* xr = x + (size_t)row * E;
  float v[12]; float s = 0.f;
  #pragma unroll
  for (int i = 0; i < 12; i++){ v[i] = xr[lane + i*64]; s += v[i]; }
  #pragma unroll
  for (int off = 32; off > 0; off >>= 1) s += __shfl_xor(s, off);
  const float mean = s * (1.0f / E);
  float vs = 0.f;
  #pragma unroll
  for (int i = 0; i < 12; i++){ float d = v[i] - mean; vs += d * d; }
  #pragma unroll
  for (int off = 32; off > 0; off >>= 1) vs += __shfl_xor(vs, off);
  const float rstd = rsqrtf(vs * (1.0f / E) + 1e-5f);
  u16* orow = o + (size_t)row * E;
  #pragma unroll
  for (int i = 0; i < 12; i++){
    int c = lane + i*64;
    orow[c] = f2bf((v[i] - mean) * rstd * ldw(g, goff + c, f32w) + ldw(b, boff + c, f32w));
  }
}

// ---------------- MFMA GEMM, 64x128 tile (occupancy-oriented) ----------------
// EPI 0: bf16 | 1: f32 atomicAdd | 2: f32 gelu | 3: bf16 *= gelu | 4: flag? f32 : bf16
template<int EPI>
__global__ __launch_bounds__(256)
void gemm_bt(const u16* __restrict__ A, const u16* __restrict__ Bm,
             const void* __restrict__ bias, size_t biasoff,
             const unsigned int* __restrict__ flag,
             u16* __restrict__ outb, float* __restrict__ outf,
             int M, int N, int K){
  __shared__ __align__(16) u16 As[2*64*32];
  __shared__ __align__(16) u16 Bs[2*128*32];
  const int t = threadIdx.x;
  const int lane = t & 63;
  const int col = lane & 15, quad = lane >> 4;
  const int wave = t >> 6;
  const int wr = (wave >> 1) * 32, wc = (wave & 1) * 64;
  const int row0 = blockIdx.y * 64, col0 = blockIdx.x * 128;
  const int f32w = (int)*flag;

  int kb = 0, ke = K;
  if (gridDim.z > 1){ const int kc = K / (int)gridDim.z; kb = blockIdx.z * kc; ke = kb + kc; }

  const int sr = t >> 2;            // staging: 4 lanes/row, 16B each
  const int sc = (t & 3) * 8;
  const u16* Ag = A + (size_t)(row0 + sr) * K + sc;
  const u16* Bg = Bm + (size_t)(col0 + sr) * K + sc;

  f32x4 acc[2][4];
  #pragma unroll
  for (int i = 0; i < 2; i++)
    #pragma unroll
    for (int j = 0; j < 4; j++) acc[i][j] = (f32x4){0.f,0.f,0.f,0.f};

  gload16(Ag + kb,                As + wave*512);
  gload16(Bg + kb,                Bs + wave*512);
  gload16(Bg + (size_t)64*K + kb, Bs + wave*512 + 2048);

  int p = 0;
  for (int k0 = kb; k0 < ke; k0 += 32, p ^= 1){
    if (k0 + 32 < ke){
      const int nxa = (p ^ 1) * 2048, nxb = (p ^ 1) * 4096;
      gload16(Ag + k0 + 32,                As + nxa + wave*512);
      gload16(Bg + k0 + 32,                Bs + nxb + wave*512);
      gload16(Bg + (size_t)64*K + k0 + 32, Bs + nxb + wave*512 + 2048);
      asm volatile("s_waitcnt vmcnt(3)\n\ts_barrier" ::: "memory");
    } else {
      asm volatile("s_waitcnt vmcnt(0)\n\ts_barrier" ::: "memory");
    }
    const u16* Ab = As + p*2048;
    const u16* Bb = Bs + p*4096;
    bf16x8 af[2], bfr[4];
    #pragma unroll
    for (int i = 0; i < 2; i++)
      af[i] = *(const bf16x8*)(Ab + (wr + i*16 + col)*32 + quad*8);
    #pragma unroll
    for (int j = 0; j < 4; j++)
      bfr[j] = *(const bf16x8*)(Bb + (wc + j*16 + col)*32 + quad*8);
    #pragma unroll
    for (int i = 0; i < 2; i++)
      #pragma unroll
      for (int j = 0; j < 4; j++)
        acc[i][j] = MFMA_BF16(af[i], bfr[j], acc[i][j]);
    asm volatile("s_waitcnt lgkmcnt(0)\n\ts_barrier" ::: "memory");
  }

  #pragma unroll
  for (int j = 0; j < 4; j++){
    const int c = col0 + wc + j*16 + col;
    const float bb = (gridDim.z > 1 && blockIdx.z != 0) ? 0.f : ldw(bias, biasoff + c, f32w);
    #pragma unroll
    for (int i = 0; i < 2; i++){
      const int r0 = row0 + wr + i*16 + quad*4;
      #pragma unroll
      for (int rr = 0; rr < 4; rr++){
        const float v = acc[i][j][rr] + bb;
        const size_t idx = (size_t)(r0 + rr) * N + c;
        if (EPI == 0)      outb[idx] = f2bf(v);
        else if (EPI == 1) atomicAdd(&outf[idx], v);
        else if (EPI == 2) outf[idx] = gelu_exact(v);
        else if (EPI == 3) outb[idx] = f2bf(bf2f(outb[idx]) * gelu_exact(v));
        else { if (f32w) outf[idx] = v; else outb[idx] = f2bf(v); }
      }
    }
  }
}

// ---------------- V transpose: Vt[h][d][j] ----------------
__global__ __launch_bounds__(256)
void vt_kernel(const u16* __restrict__ qkv, u16* __restrict__ Vt){
  const int h = blockIdx.x;
  const int t = threadIdx.x;
  const int d = t & 63;
  const int j0 = blockIdx.y * 32 + (t >> 6) * 8;
  __align__(16) u16 tmp[8];
  #pragma unroll
  for (int jj = 0; jj < 8; jj++)
    tmp[jj] = qkv[(size_t)(j0 + jj) * LDQKV + 2*E + h*64 + d];
  *(uint4*)(Vt + (size_t)(h*64 + d) * L + j0) = *(const uint4*)(tmp);
}

// ---------------- MFMA flash attention, v3 ----------------
// 256 threads, 4 waves: waves 0-1 = keys [0,1024), waves 2-3 = keys [1024,2048),
// each wave owns 16 q rows (QBLK=32). Grid = NH*L/32 = 768 = exactly 3 blocks/CU.
// K/V staged via global_load_lds with pre-swizzled per-lane global source +
// linear LDS dest (fragment order falls out; zero write bank conflicts).
// Single-buffered tiles; split K/V issue with counted vmcnt(4).
__global__ __launch_bounds__(256, 3)
void attn_mfma(const u16* __restrict__ qkv, const u16* __restrict__ Vt,
               const float* __restrict__ biasH, u16* __restrict__ outp){
  const int bid = blockIdx.x;                       // 0..767
  const int tidx = (bid & 7) * 96 + (bid >> 3);     // XCD-cluster swizzle (bijective)
  const int head = tidx >> 6;
  const int yt = tidx & 63;
  const int t = threadIdx.x;
  const int wave = t >> 6, lane = t & 63;
  const int grp = wave >> 1, w2 = wave & 1;
  const int col = lane & 15, quad = lane >> 4;
  const int q0 = yt * 32 + w2 * 16;
  const int kbeg = grp * (L/2);

  __shared__ __align__(16) u16 Kf[2][64*64];   // per group, frag order (8KB each)
  __shared__ __align__(16) u16 Vf[2][64*64];
  __shared__ __align__(16) u16 Pf[4][16*64];   // per wave, A-frag order
  u16* Kg_ = Kf[grp];
  u16* Vg_ = Vf[grp];
  u16* P = Pf[wave];

  const float scale2 = 0.125f * LOG2E;
  const float* bH = biasH + (size_t)head * L + kbeg;

  const u16* qrow = qkv + (size_t)(q0 + col) * LDQKV + head*64;
  const bf16x8 qf0 = *(const bf16x8*)(qrow + quad*8);
  const bf16x8 qf1 = *(const bf16x8*)(qrow + 32 + quad*8);

  const u16* kbase  = qkv + E + head*64;
  const u16* vtbase = Vt + (size_t)(head*64) * L;

  // staging source map (inverse of frag layout): wave w2 / instr i / lane ->
  // LDS slot i*128 + w2*64 + lane; K granule = K[kt+i*16+col][(w2*4+quad)*8..+7]
  const int dof = (w2*4 + quad) * 8;
  const u16* kG = kbase  + (size_t)(kbeg + col) * LDQKV + dof;
  const u16* vG = vtbase + (size_t)col * L + kbeg + dof;

#define ISSUE_K(kt_) { _Pragma("unroll") for (int i = 0; i < 4; i++) \
    gload16(kG + (size_t)((kt_) + i*16) * LDQKV, Kg_ + i*1024 + w2*512); }
#define ISSUE_V(kt_) { _Pragma("unroll") for (int i = 0; i < 4; i++) \
    gload16(vG + (size_t)(i*16) * L + (kt_), Vg_ + i*1024 + w2*512); }

  float m_i = -1e30f, l_i = 0.f;
  f32x4 oacc[4];
  #pragma unroll
  for (int nt = 0; nt < 4; nt++) oacc[nt] = (f32x4){0.f,0.f,0.f,0.f};

  ISSUE_K(0);
  ISSUE_V(0);

  for (int kt = 0; kt < L/2; kt += 64){
    const bool more = (kt + 64 < L/2);
    // K tile ready block-wide (V of this tile still in flight)
    asm volatile("s_waitcnt vmcnt(4)\n\ts_barrier" ::: "memory");

    // ---- swapped QK^T: s[nt][r] = S[k=kt+nt*16+quad*4+r][q=q0+col] ----
    f32x4 s[4];
    #pragma unroll
    for (int nt = 0; nt < 4; nt++){
      const bf16x8 kf0 = *(const bf16x8*)(Kg_ + nt*1024 + lane*8);
      const bf16x8 kf1 = *(const bf16x8*)(Kg_ + nt*1024 + 512 + lane*8);
      f32x4 z = (f32x4){0.f,0.f,0.f,0.f};
      z = MFMA_BF16(kf0, qf0, z);
      z = MFMA_BF16(kf1, qf1, z);
      s[nt] = z;
    }
    // K reads done block-wide -> safe to DMA next K tile
    asm volatile("s_waitcnt lgkmcnt(0)\n\ts_barrier" ::: "memory");
    if (more) ISSUE_K(kt + 64);

    // ---- bias: 1 fma per score ----
    float sv[16];
    #pragma unroll
    for (int nt = 0; nt < 4; nt++){
      const float4 bv = *(const float4*)(bH + kt + nt*16 + quad*4);
      sv[nt*4+0] = fmaf(s[nt][0], scale2, bv.x);
      sv[nt*4+1] = fmaf(s[nt][1], scale2, bv.y);
      sv[nt*4+2] = fmaf(s[nt][2], scale2, bv.z);
      sv[nt*4+3] = fmaf(s[nt][3], scale2, bv.w);
    }
    // ---- in-lane max tree + cross-quad reduce (q fixed per lane) ----
    float t8[8];
    #pragma unroll
    for (int i = 0; i < 8; i++) t8[i] = fmaxf(sv[i], sv[i+8]);
    float t4a = fmaxf(t8[0], t8[4]), t4b = fmaxf(t8[1], t8[5]);
    float t4c = fmaxf(t8[2], t8[6]), t4d = fmaxf(t8[3], t8[7]);
    float mx = fmaxf(fmaxf(t4a, t4b), fmaxf(t4c, t4d));
    mx = fmaxf(mx, __shfl_xor(mx, 16));
    mx = fmaxf(mx, __shfl_xor(mx, 32));
    const float mnew = fmaxf(m_i, mx);
    const float a = exp2f(m_i - mnew);
    m_i = mnew;
    // ---- exp2 + packed P write (4x ds_write_b64/tile) ----
    float ps = 0.f;
    #pragma unroll
    for (int nt = 0; nt < 4; nt++){
      const float e0 = exp2f(sv[nt*4+0] - mnew);
      const float e1 = exp2f(sv[nt*4+1] - mnew);
      const float e2 = exp2f(sv[nt*4+2] - mnew);
      const float e3 = exp2f(sv[nt*4+3] - mnew);
      unsigned int plo, phi;
      asm("v_cvt_pk_bf16_f32 %0, %1, %2" : "=v"(plo) : "v"(e0), "v"(e1));
      asm("v_cvt_pk_bf16_f32 %0, %1, %2" : "=v"(phi) : "v"(e2), "v"(e3));
      *(uint2*)(P + ((nt*2 + (quad >> 1))*16 + col)*8 + (quad & 1)*4) =
          make_uint2(plo, phi);
      ps += (e0 + e1) + (e2 + e3);
    }
    ps += __shfl_xor(ps, 16);
    ps += __shfl_xor(ps, 32);
    l_i = l_i * a + ps;
    float al[4];
    #pragma unroll
    for (int r = 0; r < 4; r++) al[r] = __shfl(a, quad*4 + r);
    #pragma unroll
    for (int nt = 0; nt < 4; nt++)
      #pragma unroll
      for (int r = 0; r < 4; r++) oacc[nt][r] *= al[r];

    // V tile ready block-wide (next K in flight); P writes drained (lgkm)
    if (more) asm volatile("s_waitcnt vmcnt(4) lgkmcnt(0)\n\ts_barrier" ::: "memory");
    else      asm volatile("s_waitcnt vmcnt(0) lgkmcnt(0)\n\ts_barrier" ::: "memory");

    // ---- PV: O += P[16x64] @ V[64x64] ----
    const bf16x8 pa0 = *(const bf16x8*)(P + lane*8);
    const bf16x8 pa1 = *(const bf16x8*)(P + 512 + lane*8);
    #pragma unroll
    for (int nt = 0; nt < 4; nt++){
      const bf16x8 vb0 = *(const bf16x8*)(Vg_ + nt*1024 + lane*8);
      const bf16x8 vb1 = *(const bf16x8*)(Vg_ + nt*1024 + 512 + lane*8);
      oacc[nt] = MFMA_BF16(pa0, vb0, oacc[nt]);
      oacc[nt] = MFMA_BF16(pa1, vb1, oacc[nt]);
    }
    // V/P reads done block-wide -> safe to DMA next V tile
    asm volatile("s_waitcnt lgkmcnt(0)\n\ts_barrier" ::: "memory");
    if (more) ISSUE_V(kt + 64);
  }
#undef ISSUE_K
#undef ISSUE_V

  // ---- merge the two KV halves (K/V LDS dead; vmcnt drained at loop exit) ----
  float* cO = (float*)&Kf[0][0];   // 2 waves x 64 lanes x 16 f32 = 8KB
  float* cm = (float*)&Vf[0][0];   // 2 x 16
  float* cl = cm + 32;
  if (grp == 1){
    #pragma unroll
    for (int nt = 0; nt < 4; nt++)
      #pragma unroll
      for (int r = 0; r < 4; r++)
        cO[(size_t)(w2*64 + lane)*16 + nt*4 + r] = oacc[nt][r];
    if (quad == 0){ cm[w2*16 + col] = m_i; cl[w2*16 + col] = l_i; }
  }
  __syncthreads();
  if (grp == 0){
    const float m1 = cm[w2*16 + col], l1 = cl[w2*16 + col];
    const float M = fmaxf(m_i, m1);
    const float c0 = exp2f(m_i - M), c1 = exp2f(m1 - M);
    const float inv = 1.0f / (l_i * c0 + l1 * c1);
    const float w0 = c0 * inv, w1 = c1 * inv;
    float s0[4], s1[4];
    #pragma unroll
    for (int r = 0; r < 4; r++){
      s0[r] = __shfl(w0, quad*4 + r);
      s1[r] = __shfl(w1, quad*4 + r);
    }
    #pragma unroll
    for (int nt = 0; nt < 4; nt++)
      #pragma unroll
      for (int r = 0; r < 4; r++){
        const float o1 = cO[(size_t)(w2*64 + lane)*16 + nt*4 + r];
        const int row = q0 + quad*4 + r;
        outp[(size_t)row * E + head*64 + nt*16 + col] =
            f2bf(oacc[nt][r] * s0[r] + o1 * s1[r]);
      }
  }
}

extern "C" void kernel_launch(void* const* d_in, const int* in_sizes, int n_in,
                              void* d_out, int out_size, void* d_ws, size_t ws_size,
                              hipStream_t stream){
  const int* tokens = (const int*)d_in[0];
  const int* amask  = (const int*)d_in[1];

  // ---- ws: flag | biasH | x f32 | hbuf bf16 | Vt bf16 | weight casts ----
  unsigned int* flag = (unsigned int*)d_ws;
  float* biasH = (float*)((char*)d_ws + 256);
  float* x   = biasH + (size_t)NH*L;
  u16* hbuf  = (u16*)(x + (size_t)L*E);
  u16* vtb   = hbuf + (size_t)L*E;
  u16* wc    = vtb + (size_t)NH*64*L;

  const size_t N_INW  = (size_t)NL*3*E*E;
  const size_t N_OUTW = (size_t)NL*E*E;
  const size_t N_FW1  = (size_t)NL*2*FFN*E;
  const size_t N_FW2  = (size_t)NL*E*FFN;
  const size_t N_MW1  = (size_t)E*E;
  const size_t N_MW2  = (size_t)VOC*E;
  u16* in_w  = wc;                 wc += N_INW;
  u16* out_w = wc;                 wc += N_OUTW;
  u16* ffw1  = wc;                 wc += N_FW1;
  u16* ffw2  = wc;                 wc += N_FW2;
  u16* mw1   = wc;                 wc += N_MW1;
  u16* mw2   = wc;                 wc += N_MW2;

  // ---- activations in d_out (high-water 16.8 MB) ----
  u16* qkvb  = (u16*)d_out;
  u16* attnb = (u16*)d_out + (size_t)L*LDQKV;
  u16* abuf  = (u16*)d_out;
  float* tbuf = (float*)d_out;

  const int o1 = (int)(N_INW/4);
  const int o2 = o1 + (int)(N_OUTW/4);
  const int o3 = o2 + (int)(N_FW1/4);
  const int o4 = o3 + (int)(N_FW2/4);
  const int o5 = o4 + (int)(N_MW1/4);
  const int o6 = o5 + (int)(N_MW2/4);

  detect_kernel<<<1, 256, 0, stream>>>((const u16*)d_in[2], flag);
  bias_kernel<<<NH*L/256, 256, 0, stream>>>(amask, biasH);
  cast_all<<<(o6 + 255)/256, 256, 0, stream>>>(d_in[5], d_in[7], d_in[11], d_in[13],
      d_in[17], d_in[21], in_w, o1, o2, o3, o4, o5, o6, flag);

  embed_kernel<<<L*E/256, 256, 0, stream>>>(tokens, d_in[2], flag, x);

  for (int ly = 0; ly < NL; ly++){
    ln_kernel<<<L/4, 256, 0, stream>>>(x, d_in[3], d_in[4],
        (size_t)ly*E, (size_t)ly*E, flag, hbuf);
    gemm_bt<0><<<dim3(3*E/128, L/64), 256, 0, stream>>>(hbuf, in_w + (size_t)ly*3*E*E,
        d_in[6], (size_t)ly*3*E, flag, qkvb, nullptr, L, 3*E, E);
    vt_kernel<<<dim3(NH, L/32), 256, 0, stream>>>(qkvb, vtb);
    attn_mfma<<<dim3(NH * (L/32)), 256, 0, stream>>>(qkvb, vtb, biasH, attnb);
    gemm_bt<1><<<dim3(E/128, L/64, 2), 256, 0, stream>>>(attnb, out_w + (size_t)ly*E*E,
        d_in[8], (size_t)ly*E, flag, nullptr, x, L, E, E);
    ln_kernel<<<L/4, 256, 0, stream>>>(x, d_in[9], d_in[10],
        (size_t)ly*E, (size_t)ly*E, flag, hbuf);
    gemm_bt<0><<<dim3(FFN/128, L/64), 256, 0, stream>>>(hbuf,
        ffw1 + (size_t)ly*2*FFN*E, d_in[12], (size_t)ly*2*FFN, flag,
        abuf, nullptr, L, FFN, E);
    gemm_bt<3><<<dim3(FFN/128, L/64), 256, 0, stream>>>(hbuf,
        ffw1 + (size_t)ly*2*FFN*E + (size_t)FFN*E, d_in[12], (size_t)ly*2*FFN + FFN, flag,
        abuf, nullptr, L, FFN, E);
    gemm_bt<1><<<dim3(E/128, L/64, 2), 256, 0, stream>>>(abuf, ffw2 + (size_t)ly*E*FFN,
        d_in[14], (size_t)ly*E, flag, nullptr, x, L, E, FFN);
  }
  ln_kernel<<<L/4, 256, 0, stream>>>(x, d_in[15], d_in[16], 0, 0, flag, hbuf);
  gemm_bt<2><<<dim3(E/128, L/64), 256, 0, stream>>>(hbuf, mw1,
      d_in[18], 0, flag, nullptr, tbuf, L, E, E);
  ln_kernel<<<L/4, 256, 0, stream>>>(tbuf, d_in[19], d_in[20], 0, 0, flag, hbuf);
  gemm_bt<4><<<dim3(VOC/128, L/64), 256, 0, stream>>>(hbuf, mw2,
      d_in[22], 0, flag, (u16*)d_out, (float*)d_out, L, VOC, E);
}